// Round 18
// baseline (292.080 us; speedup 1.0000x reference)
//
#include <hip/hip_runtime.h>
#include <hip/hip_bf16.h>

typedef _Float16 half8 __attribute__((ext_vector_type(8)));
typedef float f32x4 __attribute__((ext_vector_type(4)));

#define NN 50000
#define NE 800000

// fast swish: v * rcp(1+exp(-v))
__device__ __forceinline__ float swishf(float v) {
  return v * __builtin_amdgcn_rcpf(1.f + __expf(-v));
}

// ---------------------------------------------------------------------------
// prep: grid-sliced combo kernel.
//   blocks [0,12500)  : linear_up  (xbuf = nf @ W_up, f16)
//   blocks [12500,12510): pack W3/W2 into MFMA-B fragment order
// ---------------------------------------------------------------------------
__global__ __launch_bounds__(256)
void prep_kernel(const float* __restrict__ nf, const float* __restrict__ W_up,
                 _Float16* __restrict__ xbuf, const float* __restrict__ W3,
                 const float* __restrict__ W2, _Float16* __restrict__ w3p,
                 _Float16* __restrict__ w2p) {
  const int b = blockIdx.x, tid = threadIdx.x;
  if (b < 12500) {
    const int gid = b * 256 + tid;
    const int row = gid >> 6, lane = tid & 63;
    const float* xr = nf + (long)row * 64;
    float acc = 0.f;
#pragma unroll
    for (int k = 0; k < 64; ++k) acc = fmaf(xr[k], W_up[k * 64 + lane], acc);
    xbuf[(long)row * 64 + lane] = (_Float16)acc;
  } else {
    const int bb = b - 12500;
    if (bb < 8) {
      int t = bb * 256 + tid;
      int lane = t & 63, nt = (t >> 6) & 3, ks = t >> 8;
      int f = 16 * nt + (lane & 15);
      int jb = 32 * ks + 8 * (lane >> 4);
#pragma unroll
      for (int u = 0; u < 8; ++u) {
        int j = jb + u;
        w3p[t * 8 + u] = (_Float16)W3[(j >> 2) * 256 + 4 * f + (j & 3)];
      }
    } else {
      int t = (bb - 8) * 256 + tid;
      if (t < 512) {
        int lane = t & 63, nt = (t >> 6) & 3, kk = t >> 8;
        int c = 16 * nt + (lane & 15);
        int kb = 32 * kk + 8 * (lane >> 4);
#pragma unroll
        for (int u = 0; u < 8; ++u)
          w2p[t * 8 + u] = (_Float16)W2[(kb + u) * 64 + c];
      }
    }
  }
}

// ---------------------------------------------------------------------------
// linear_down: out[row] = (X[row] @ W) / 16   (f32 in/out)
// ---------------------------------------------------------------------------
__global__ __launch_bounds__(256)
void linear_down_kernel(const float* __restrict__ X, const float* __restrict__ W,
                        float* __restrict__ Y) {
  int gid = blockIdx.x * 256 + (int)threadIdx.x;
  int row = gid >> 6;
  int lane = threadIdx.x & 63;
  const float* xr = X + (long)row * 64;
  float acc = 0.f;
#pragma unroll
  for (int k = 0; k < 64; ++k) acc = fmaf(xr[k], W[k * 64 + lane], acc);
  Y[(long)row * 64 + lane] = acc * 0.0625f;
}

// ---------------------------------------------------------------------------
// fused_tp v8: r12/r17 pipeline (128 edges/block, 2 M-tiles/wave, zero
// barriers) with the r6-verified f32 ATOMIC epilogue: acc*x_s scattered
// straight into agg[rcv] (fire-and-forget unsafeAtomicAdd). No CSR build,
// no msg buffer, no gather pass. Atomic drain measured at ~1.08 TB/s (r6).
// ---------------------------------------------------------------------------
__global__ __launch_bounds__(256, 4)
void fused_tp_kernel(const float* __restrict__ rad, const float* __restrict__ ef,
                     const _Float16* __restrict__ xup, const int* __restrict__ snd,
                     const int* __restrict__ rcv, const int* __restrict__ msk,
                     const float* __restrict__ W1,
                     const _Float16* __restrict__ w2p, const _Float16* __restrict__ w3p,
                     float* __restrict__ agg) {
  __shared__ float    s_ef[128][4];    // 2 KB
  __shared__ _Float16 s_xs[128][72];   // 18.4 KB
  __shared__ _Float16 s_hp[128][72];   // 18.4 KB

  const int t = threadIdx.x;
  const long e0 = (long)blockIdx.x * 128;
  const int w = t >> 6, lane = t & 63, m = lane & 15, g = lane >> 4;
  const int ew0 = 32 * w;              // wave's 32-edge slab base row

  // ---- stage (ALL wave-local, no barriers) ----
  {
    // ef: 2 floats per lane
    const float2 e2 = *reinterpret_cast<const float2*>(ef + (e0 + ew0) * 4 + lane * 2);
    const int rr = ew0 + (lane >> 1), rc = 2 * (lane & 1);
    s_ef[rr][rc] = e2.x;
    s_ef[rr][rc + 1] = e2.y;
    // x_s gather: 2 lanes per edge, 64B each
    const int e = ew0 + (lane >> 1), q2 = lane & 1;
    const int sn = snd[e0 + e];
    const int mk = msk[e0 + e];
    uint4 v0 = {0,0,0,0}, v1 = {0,0,0,0}, v2 = {0,0,0,0}, v3 = {0,0,0,0};
    if (mk) {
      const uint4* src = reinterpret_cast<const uint4*>(xup + (long)sn * 64 + q2 * 32);
      v0 = src[0]; v1 = src[1]; v2 = src[2]; v3 = src[3];
    }
    uint4* dst = reinterpret_cast<uint4*>(&s_xs[e][q2 * 32]);
    dst[0] = v0; dst[1] = v1; dst[2] = v2; dst[3] = v3;
  }

  const int em0 = ew0 + m;        // tile-0 A row
  const int em1 = ew0 + 16 + m;   // tile-1 A row

  // ---- h1 in registers for BOTH tiles (shared W1 loads) ----
  float rv0[8], rv1[8];
  {
    const float4 a = *reinterpret_cast<const float4*>(rad + (e0 + em0) * 8);
    const float4 b = *reinterpret_cast<const float4*>(rad + (e0 + em0) * 8 + 4);
    const float4 c = *reinterpret_cast<const float4*>(rad + (e0 + em1) * 8);
    const float4 d = *reinterpret_cast<const float4*>(rad + (e0 + em1) * 8 + 4);
    rv0[0]=a.x; rv0[1]=a.y; rv0[2]=a.z; rv0[3]=a.w;
    rv0[4]=b.x; rv0[5]=b.y; rv0[6]=b.z; rv0[7]=b.w;
    rv1[0]=c.x; rv1[1]=c.y; rv1[2]=c.z; rv1[3]=c.w;
    rv1[4]=d.x; rv1[5]=d.y; rv1[6]=d.z; rv1[7]=d.w;
  }

  half8 af0[2], af1[2];
#pragma unroll
  for (int kk = 0; kk < 2; ++kk) {
    float a0[8], a1[8];
#pragma unroll
    for (int u = 0; u < 8; ++u) { a0[u] = 0.f; a1[u] = 0.f; }
#pragma unroll
    for (int k = 0; k < 8; ++k) {
      const float4 wa = *reinterpret_cast<const float4*>(W1 + k * 64 + 32 * kk + 8 * g);
      const float4 wb = *reinterpret_cast<const float4*>(W1 + k * 64 + 32 * kk + 8 * g + 4);
      a0[0] = fmaf(rv0[k], wa.x, a0[0]);  a1[0] = fmaf(rv1[k], wa.x, a1[0]);
      a0[1] = fmaf(rv0[k], wa.y, a0[1]);  a1[1] = fmaf(rv1[k], wa.y, a1[1]);
      a0[2] = fmaf(rv0[k], wa.z, a0[2]);  a1[2] = fmaf(rv1[k], wa.z, a1[2]);
      a0[3] = fmaf(rv0[k], wa.w, a0[3]);  a1[3] = fmaf(rv1[k], wa.w, a1[3]);
      a0[4] = fmaf(rv0[k], wb.x, a0[4]);  a1[4] = fmaf(rv1[k], wb.x, a1[4]);
      a0[5] = fmaf(rv0[k], wb.y, a0[5]);  a1[5] = fmaf(rv1[k], wb.y, a1[5]);
      a0[6] = fmaf(rv0[k], wb.z, a0[6]);  a1[6] = fmaf(rv1[k], wb.z, a1[6]);
      a0[7] = fmaf(rv0[k], wb.w, a0[7]);  a1[7] = fmaf(rv1[k], wb.w, a1[7]);
    }
#pragma unroll
    for (int u = 0; u < 8; ++u) {
      af0[kk][u] = (_Float16)swishf(a0[u]);
      af1[kk][u] = (_Float16)swishf(a1[u]);
    }
  }

  // ---- h2 = swish(h1 @ W2) via MFMA, w2p frags loaded ONCE for both tiles ----
  {
    half8 bw[8];
#pragma unroll
    for (int i = 0; i < 8; ++i)
      bw[i] = *reinterpret_cast<const half8*>(w2p + ((size_t)i * 64 + lane) * 8);

    f32x4 A0[4], A1[4];
#pragma unroll
    for (int nt = 0; nt < 4; ++nt) { A0[nt] = (f32x4){0.f,0.f,0.f,0.f}; A1[nt] = (f32x4){0.f,0.f,0.f,0.f}; }
#pragma unroll
    for (int kk = 0; kk < 2; ++kk) {
#pragma unroll
      for (int nt = 0; nt < 4; ++nt) {
        A0[nt] = __builtin_amdgcn_mfma_f32_16x16x32_f16(af0[kk], bw[kk * 4 + nt], A0[nt], 0, 0, 0);
        A1[nt] = __builtin_amdgcn_mfma_f32_16x16x32_f16(af1[kk], bw[kk * 4 + nt], A1[nt], 0, 0, 0);
      }
    }
    const int col = lane & 15, rg = lane >> 4;
    const int pbase = 16 * ((col >> 1) & 3) + 2 * (col >> 3) + (col & 1);
#pragma unroll
    for (int nt = 0; nt < 4; ++nt) {
      const int pos = pbase + 4 * nt;
#pragma unroll
      for (int i = 0; i < 4; ++i) {
        const int r0 = ew0 + rg * 4 + i;
        s_hp[r0][pos]      = (_Float16)swishf(A0[nt][i]);
        s_hp[r0 + 16][pos] = (_Float16)swishf(A1[nt][i]);
      }
    }
  }

  // ---- TP: msg = (A' @ W3re) * x_s, atomic scatter into agg[rcv] ----
  {
    const _Float16* hr0 = &s_hp[em0][g * 16];
    const _Float16* hr1 = &s_hp[em1][g * 16];
    half8 hlo0 = *reinterpret_cast<const half8*>(hr0);
    half8 hhi0 = *reinterpret_cast<const half8*>(hr0 + 8);
    half8 hlo1 = *reinterpret_cast<const half8*>(hr1);
    half8 hhi1 = *reinterpret_cast<const half8*>(hr1 + 8);

    _Float16 ef0[4], ef1[4];
#pragma unroll
    for (int l = 0; l < 4; ++l) {
      ef0[l] = (_Float16)s_ef[em0][l];
      ef1[l] = (_Float16)s_ef[em1][l];
    }

    f32x4 c0[4], c1[4];
#pragma unroll
    for (int nt = 0; nt < 4; ++nt) { c0[nt] = (f32x4){0.f,0.f,0.f,0.f}; c1[nt] = (f32x4){0.f,0.f,0.f,0.f}; }

#pragma unroll
    for (int ks = 0; ks < 8; ++ks) {
      half8 bfr[4];
#pragma unroll
      for (int nt = 0; nt < 4; ++nt)
        bfr[nt] = *reinterpret_cast<const half8*>(w3p + ((size_t)(ks * 4 + nt) * 64 + lane) * 8);

      const _Float16 p0  = (ks < 4) ? hlo0[2 * ks]     : hhi0[2 * (ks - 4)];
      const _Float16 p1  = (ks < 4) ? hlo0[2 * ks + 1] : hhi0[2 * (ks - 4) + 1];
      const _Float16 q0  = (ks < 4) ? hlo1[2 * ks]     : hhi1[2 * (ks - 4)];
      const _Float16 q1  = (ks < 4) ? hlo1[2 * ks + 1] : hhi1[2 * (ks - 4) + 1];
      half8 a0, a1;
#pragma unroll
      for (int l = 0; l < 4; ++l) {
        a0[l]     = p0 * ef0[l];
        a0[4 + l] = p1 * ef0[l];
        a1[l]     = q0 * ef1[l];
        a1[4 + l] = q1 * ef1[l];
      }
#pragma unroll
      for (int nt = 0; nt < 4; ++nt) {
        c0[nt] = __builtin_amdgcn_mfma_f32_16x16x32_f16(a0, bfr[nt], c0[nt], 0, 0, 0);
        c1[nt] = __builtin_amdgcn_mfma_f32_16x16x32_f16(a1, bfr[nt], c1[nt], 0, 0, 0);
      }
    }

    // epilogue: multiply x_s, fire-and-forget f32 atomics (r6-verified path)
    const int col = lane & 15, rg = lane >> 4;
    int rc0[4], rc1[4];
#pragma unroll
    for (int i = 0; i < 4; ++i) {
      rc0[i] = rcv[e0 + ew0 + rg * 4 + i];        // 16-lane broadcast loads
      rc1[i] = rcv[e0 + ew0 + 16 + rg * 4 + i];
    }
#pragma unroll
    for (int nt = 0; nt < 4; ++nt) {
      const int f = nt * 16 + col;
#pragma unroll
      for (int i = 0; i < 4; ++i) {
        const int r0 = ew0 + rg * 4 + i;
        const float v0 = c0[nt][i] * (float)s_xs[r0][f];
        const float v1 = c1[nt][i] * (float)s_xs[r0 + 16][f];
        unsafeAtomicAdd(&agg[(size_t)rc0[i] * 64 + f], v0);
        unsafeAtomicAdd(&agg[(size_t)rc1[i] * 64 + f], v1);
      }
    }
  }
}

extern "C" void kernel_launch(void* const* d_in, const int* in_sizes, int n_in,
                              void* d_out, int out_size, void* d_ws, size_t ws_size,
                              hipStream_t stream) {
  const float* nf   = (const float*)d_in[0];
  const float* ef   = (const float*)d_in[1];
  const float* rad  = (const float*)d_in[2];
  const int*   snd  = (const int*)d_in[3];
  const int*   rcv  = (const int*)d_in[4];
  const int*   msk  = (const int*)d_in[5];
  const float* W_up = (const float*)d_in[6];
  const float* W1   = (const float*)d_in[7];
  const float* W2   = (const float*)d_in[8];
  const float* W3   = (const float*)d_in[9];
  const float* W_dn = (const float*)d_in[10];
  float* out = (float*)d_out;

  // workspace layout (~19.3 MB)
  float*    agg  = (float*)d_ws;                    // 50000*64 f32 = 12.8 MB
  _Float16* xbuf = (_Float16*)(agg + (size_t)NN * 64); // 6.4 MB
  _Float16* w3p  = xbuf + (size_t)NN * 64;          // 32 KB
  _Float16* w2p  = w3p + 2048 * 8;                  // 8 KB

  hipMemsetAsync(agg, 0, (size_t)NN * 64 * sizeof(float), stream);

  // linear_up + weight pack in one grid-sliced launch
  prep_kernel<<<12510, 256, 0, stream>>>(nf, W_up, xbuf, W3, W2, w3p, w2p);

  // fused radial MLP + TP + atomic scatter
  fused_tp_kernel<<<NE / 128, 256, 0, stream>>>(rad, ef, xbuf, snd, rcv, msk,
                                                W1, w2p, w3p, agg);

  // out = (agg / 16) @ W_down
  linear_down_kernel<<<(NN * 64) / 256, 256, 0, stream>>>(agg, W_dn, out);
}

// Round 19
// 239.984 us; speedup vs baseline: 1.2171x; 1.2171x over previous
//
#include <hip/hip_runtime.h>
#include <hip/hip_bf16.h>

typedef _Float16 half8 __attribute__((ext_vector_type(8)));
typedef _Float16 half4v __attribute__((ext_vector_type(4)));
typedef float f32x4 __attribute__((ext_vector_type(4)));

#define NN 50000
#define NE 800000

// fast swish: v * rcp(1+exp(-v))
__device__ __forceinline__ float swishf(float v) {
  return v * __builtin_amdgcn_rcpf(1.f + __expf(-v));
}

// ---------------------------------------------------------------------------
// prep: grid-sliced combo kernel.
//   blocks [0,12500)      : linear_up  (xbuf = nf @ W_up, f16)
//   blocks [12500,15625)  : hist       (deg[rcv[e]]++ ; 3125*256 = NE exact)
//   blocks [15625,15635)  : pack W3/W2 into MFMA-B fragment order
// ---------------------------------------------------------------------------
__global__ __launch_bounds__(256)
void prep_kernel(const float* __restrict__ nf, const float* __restrict__ W_up,
                 _Float16* __restrict__ xbuf, const int* __restrict__ rcv,
                 int* __restrict__ deg, const float* __restrict__ W3,
                 const float* __restrict__ W2, _Float16* __restrict__ w3p,
                 _Float16* __restrict__ w2p) {
  const int b = blockIdx.x, tid = threadIdx.x;
  if (b < 12500) {
    const int gid = b * 256 + tid;
    const int row = gid >> 6, lane = tid & 63;
    const float* xr = nf + (long)row * 64;
    float acc = 0.f;
#pragma unroll
    for (int k = 0; k < 64; ++k) acc = fmaf(xr[k], W_up[k * 64 + lane], acc);
    xbuf[(long)row * 64 + lane] = (_Float16)acc;
  } else if (b < 15625) {
    const int e = (b - 12500) * 256 + tid;
    atomicAdd(&deg[rcv[e]], 1);
  } else {
    const int bb = b - 15625;
    if (bb < 8) {
      int t = bb * 256 + tid;
      int lane = t & 63, nt = (t >> 6) & 3, ks = t >> 8;
      int f = 16 * nt + (lane & 15);
      int jb = 32 * ks + 8 * (lane >> 4);
#pragma unroll
      for (int u = 0; u < 8; ++u) {
        int j = jb + u;
        w3p[t * 8 + u] = (_Float16)W3[(j >> 2) * 256 + 4 * f + (j & 3)];
      }
    } else {
      int t = (bb - 8) * 256 + tid;
      if (t < 512) {
        int lane = t & 63, nt = (t >> 6) & 3, kk = t >> 8;
        int c = 16 * nt + (lane & 15);
        int kb = 32 * kk + 8 * (lane >> 4);
#pragma unroll
        for (int u = 0; u < 8; ++u)
          w2p[t * 8 + u] = (_Float16)W2[(kb + u) * 64 + c];
      }
    }
  }
}

// ---------------------------------------------------------------------------
// CSR offsets: 3-phase coalesced scan over per-node degrees
// ---------------------------------------------------------------------------
__global__ __launch_bounds__(256)
void scan1_kernel(const int* __restrict__ deg, int* __restrict__ bsum) {
  __shared__ int s[256];
  int gid = blockIdx.x * 256 + threadIdx.x;
  s[threadIdx.x] = (gid < NN) ? deg[gid] : 0;
  __syncthreads();
  for (int d = 128; d > 0; d >>= 1) {
    if (threadIdx.x < d) s[threadIdx.x] += s[threadIdx.x + d];
    __syncthreads();
  }
  if (threadIdx.x == 0) bsum[blockIdx.x] = s[0];
}

__global__ __launch_bounds__(256)
void scan2_kernel(const int* __restrict__ bsum, int* __restrict__ boff) {
  __shared__ int s[256];
  int t = threadIdx.x;
  int v = (t < 196) ? bsum[t] : 0;
  s[t] = v;
  __syncthreads();
  for (int d = 1; d < 256; d <<= 1) {
    int x = (t >= d) ? s[t - d] : 0;
    __syncthreads();
    s[t] += x;
    __syncthreads();
  }
  boff[t] = s[t] - v;   // exclusive
}

__global__ __launch_bounds__(256)
void scan3_kernel(const int* __restrict__ deg, const int* __restrict__ boff,
                  int* __restrict__ pos, int* __restrict__ cur) {
  __shared__ int s[256];
  int t = threadIdx.x, gid = blockIdx.x * 256 + t;
  int v = (gid < NN) ? deg[gid] : 0;
  s[t] = v;
  __syncthreads();
  for (int d = 1; d < 256; d <<= 1) {
    int x = (t >= d) ? s[t - d] : 0;
    __syncthreads();
    s[t] += x;
    __syncthreads();
  }
  int ex = s[t] - v + boff[blockIdx.x];
  if (gid < NN) {
    pos[gid] = ex;
    cur[gid] = ex;
    if (gid == NN - 1) pos[NN] = ex + v;
  }
}

// ---------------------------------------------------------------------------
// fused_tp (r12 verbatim -- best measured config, 139-141 us):
// 128 edges/block, 4 waves, 32 edges (2 M-tiles) per wave, zero barriers.
// msg rows written to CSR slots (receiver-sorted) -> gather side is
// fully sequential and needs NO edge-index array.
// ---------------------------------------------------------------------------
__global__ __launch_bounds__(256, 4)
void fused_tp_kernel(const float* __restrict__ rad, const float* __restrict__ ef,
                     const _Float16* __restrict__ xup, const int* __restrict__ snd,
                     const int* __restrict__ rcv, const int* __restrict__ msk,
                     const float* __restrict__ W1,
                     const _Float16* __restrict__ w2p, const _Float16* __restrict__ w3p,
                     int* __restrict__ cur, _Float16* __restrict__ msg) {
  __shared__ float    s_ef[128][4];    // 2 KB
  __shared__ _Float16 s_xs[128][72];   // 18.4 KB
  __shared__ _Float16 s_hp[128][72];   // 18.4 KB
  __shared__ int      s_slot[128];     // 0.5 KB

  const int t = threadIdx.x;
  const long e0 = (long)blockIdx.x * 128;
  const int w = t >> 6, lane = t & 63, m = lane & 15, g = lane >> 4;
  const int ew0 = 32 * w;              // wave's 32-edge slab base row

  // ---- stage (ALL wave-local, no barriers) ----
  {
    // ef: 2 floats per lane
    const float2 e2 = *reinterpret_cast<const float2*>(ef + (e0 + ew0) * 4 + lane * 2);
    const int rr = ew0 + (lane >> 1), rc = 2 * (lane & 1);
    s_ef[rr][rc] = e2.x;
    s_ef[rr][rc + 1] = e2.y;
    // CSR slot atomics: lanes 0..31, one per own edge
    if (lane < 32) s_slot[ew0 + lane] = atomicAdd(&cur[rcv[e0 + ew0 + lane]], 1);
    // x_s gather: 2 lanes per edge, 64B each
    const int e = ew0 + (lane >> 1), q2 = lane & 1;
    const int sn = snd[e0 + e];
    const int mk = msk[e0 + e];
    uint4 v0 = {0,0,0,0}, v1 = {0,0,0,0}, v2 = {0,0,0,0}, v3 = {0,0,0,0};
    if (mk) {
      const uint4* src = reinterpret_cast<const uint4*>(xup + (long)sn * 64 + q2 * 32);
      v0 = src[0]; v1 = src[1]; v2 = src[2]; v3 = src[3];
    }
    uint4* dst = reinterpret_cast<uint4*>(&s_xs[e][q2 * 32]);
    dst[0] = v0; dst[1] = v1; dst[2] = v2; dst[3] = v3;
  }

  const int em0 = ew0 + m;        // tile-0 A row
  const int em1 = ew0 + 16 + m;   // tile-1 A row

  // ---- h1 in registers for BOTH tiles (shared W1 loads) ----
  float rv0[8], rv1[8];
  {
    const float4 a = *reinterpret_cast<const float4*>(rad + (e0 + em0) * 8);
    const float4 b = *reinterpret_cast<const float4*>(rad + (e0 + em0) * 8 + 4);
    const float4 c = *reinterpret_cast<const float4*>(rad + (e0 + em1) * 8);
    const float4 d = *reinterpret_cast<const float4*>(rad + (e0 + em1) * 8 + 4);
    rv0[0]=a.x; rv0[1]=a.y; rv0[2]=a.z; rv0[3]=a.w;
    rv0[4]=b.x; rv0[5]=b.y; rv0[6]=b.z; rv0[7]=b.w;
    rv1[0]=c.x; rv1[1]=c.y; rv1[2]=c.z; rv1[3]=c.w;
    rv1[4]=d.x; rv1[5]=d.y; rv1[6]=d.z; rv1[7]=d.w;
  }

  half8 af0[2], af1[2];
#pragma unroll
  for (int kk = 0; kk < 2; ++kk) {
    float a0[8], a1[8];
#pragma unroll
    for (int u = 0; u < 8; ++u) { a0[u] = 0.f; a1[u] = 0.f; }
#pragma unroll
    for (int k = 0; k < 8; ++k) {
      const float4 wa = *reinterpret_cast<const float4*>(W1 + k * 64 + 32 * kk + 8 * g);
      const float4 wb = *reinterpret_cast<const float4*>(W1 + k * 64 + 32 * kk + 8 * g + 4);
      a0[0] = fmaf(rv0[k], wa.x, a0[0]);  a1[0] = fmaf(rv1[k], wa.x, a1[0]);
      a0[1] = fmaf(rv0[k], wa.y, a0[1]);  a1[1] = fmaf(rv1[k], wa.y, a1[1]);
      a0[2] = fmaf(rv0[k], wa.z, a0[2]);  a1[2] = fmaf(rv1[k], wa.z, a1[2]);
      a0[3] = fmaf(rv0[k], wa.w, a0[3]);  a1[3] = fmaf(rv1[k], wa.w, a1[3]);
      a0[4] = fmaf(rv0[k], wb.x, a0[4]);  a1[4] = fmaf(rv1[k], wb.x, a1[4]);
      a0[5] = fmaf(rv0[k], wb.y, a0[5]);  a1[5] = fmaf(rv1[k], wb.y, a1[5]);
      a0[6] = fmaf(rv0[k], wb.z, a0[6]);  a1[6] = fmaf(rv1[k], wb.z, a1[6]);
      a0[7] = fmaf(rv0[k], wb.w, a0[7]);  a1[7] = fmaf(rv1[k], wb.w, a1[7]);
    }
#pragma unroll
    for (int u = 0; u < 8; ++u) {
      af0[kk][u] = (_Float16)swishf(a0[u]);
      af1[kk][u] = (_Float16)swishf(a1[u]);
    }
  }

  // ---- h2 = swish(h1 @ W2) via MFMA, w2p frags loaded ONCE for both tiles ----
  {
    half8 bw[8];
#pragma unroll
    for (int i = 0; i < 8; ++i)
      bw[i] = *reinterpret_cast<const half8*>(w2p + ((size_t)i * 64 + lane) * 8);

    f32x4 A0[4], A1[4];
#pragma unroll
    for (int nt = 0; nt < 4; ++nt) { A0[nt] = (f32x4){0.f,0.f,0.f,0.f}; A1[nt] = (f32x4){0.f,0.f,0.f,0.f}; }
#pragma unroll
    for (int kk = 0; kk < 2; ++kk) {
#pragma unroll
      for (int nt = 0; nt < 4; ++nt) {
        A0[nt] = __builtin_amdgcn_mfma_f32_16x16x32_f16(af0[kk], bw[kk * 4 + nt], A0[nt], 0, 0, 0);
        A1[nt] = __builtin_amdgcn_mfma_f32_16x16x32_f16(af1[kk], bw[kk * 4 + nt], A1[nt], 0, 0, 0);
      }
    }
    const int col = lane & 15, rg = lane >> 4;
    const int pbase = 16 * ((col >> 1) & 3) + 2 * (col >> 3) + (col & 1);
#pragma unroll
    for (int nt = 0; nt < 4; ++nt) {
      const int pos = pbase + 4 * nt;
#pragma unroll
      for (int i = 0; i < 4; ++i) {
        const int r0 = ew0 + rg * 4 + i;
        s_hp[r0][pos]      = (_Float16)swishf(A0[nt][i]);
        s_hp[r0 + 16][pos] = (_Float16)swishf(A1[nt][i]);
      }
    }
  }

  // ---- TP: msg = (A' @ W3re) * x_s, w3p frags loaded ONCE per ks for both tiles ----
  {
    const _Float16* hr0 = &s_hp[em0][g * 16];
    const _Float16* hr1 = &s_hp[em1][g * 16];
    half8 hlo0 = *reinterpret_cast<const half8*>(hr0);
    half8 hhi0 = *reinterpret_cast<const half8*>(hr0 + 8);
    half8 hlo1 = *reinterpret_cast<const half8*>(hr1);
    half8 hhi1 = *reinterpret_cast<const half8*>(hr1 + 8);

    _Float16 ef0[4], ef1[4];
#pragma unroll
    for (int l = 0; l < 4; ++l) {
      ef0[l] = (_Float16)s_ef[em0][l];
      ef1[l] = (_Float16)s_ef[em1][l];
    }

    f32x4 c0[4], c1[4];
#pragma unroll
    for (int nt = 0; nt < 4; ++nt) { c0[nt] = (f32x4){0.f,0.f,0.f,0.f}; c1[nt] = (f32x4){0.f,0.f,0.f,0.f}; }

#pragma unroll
    for (int ks = 0; ks < 8; ++ks) {
      half8 bfr[4];
#pragma unroll
      for (int nt = 0; nt < 4; ++nt)
        bfr[nt] = *reinterpret_cast<const half8*>(w3p + ((size_t)(ks * 4 + nt) * 64 + lane) * 8);

      const _Float16 p0  = (ks < 4) ? hlo0[2 * ks]     : hhi0[2 * (ks - 4)];
      const _Float16 p1  = (ks < 4) ? hlo0[2 * ks + 1] : hhi0[2 * (ks - 4) + 1];
      const _Float16 q0  = (ks < 4) ? hlo1[2 * ks]     : hhi1[2 * (ks - 4)];
      const _Float16 q1  = (ks < 4) ? hlo1[2 * ks + 1] : hhi1[2 * (ks - 4) + 1];
      half8 a0, a1;
#pragma unroll
      for (int l = 0; l < 4; ++l) {
        a0[l]     = p0 * ef0[l];
        a0[4 + l] = p1 * ef0[l];
        a1[l]     = q0 * ef1[l];
        a1[4 + l] = q1 * ef1[l];
      }
#pragma unroll
      for (int nt = 0; nt < 4; ++nt) {
        c0[nt] = __builtin_amdgcn_mfma_f32_16x16x32_f16(a0, bfr[nt], c0[nt], 0, 0, 0);
        c1[nt] = __builtin_amdgcn_mfma_f32_16x16x32_f16(a1, bfr[nt], c1[nt], 0, 0, 0);
      }
    }

    // multiply by x_s, pack f16 into own-wave s_hp rows (LDS bounce)
    const int col = lane & 15, rg = lane >> 4;
#pragma unroll
    for (int nt = 0; nt < 4; ++nt) {
      const int f = nt * 16 + col;
#pragma unroll
      for (int i = 0; i < 4; ++i) {
        const int r0 = ew0 + rg * 4 + i;
        s_hp[r0][f]      = (_Float16)(c0[nt][i] * (float)s_xs[r0][f]);
        s_hp[r0 + 16][f] = (_Float16)(c1[nt][i] * (float)s_xs[r0 + 16][f]);
      }
    }
  }

  // ---- coalesced 128B row store to CSR slots (own-wave rows, 2 lanes/edge) ----
  {
    const int e = ew0 + (lane >> 1), q2 = lane & 1;
    const uint4* src = reinterpret_cast<const uint4*>(&s_hp[e][q2 * 32]);
    uint4 v0 = src[0], v1 = src[1], v2 = src[2], v3 = src[3];
    uint4* dst = reinterpret_cast<uint4*>(msg + (long)s_slot[e] * 64 + q2 * 32);
    dst[0] = v0; dst[1] = v1; dst[2] = v2; dst[3] = v3;
  }
}

// ---------------------------------------------------------------------------
// gather_down: block owns 16 nodes; msg rows for node n are CONTIGUOUS slots
// [pos[n], pos[n+1]) -> purely sequential reads, no index array.
// Fused /16 @ W_down -> sequential out rows.
// ---------------------------------------------------------------------------
__global__ __launch_bounds__(256, 8)
void gather_down_kernel(const _Float16* __restrict__ msg, const int* __restrict__ pos,
                        const float* __restrict__ W_dn, float* __restrict__ out) {
  __shared__ int   s_pos[17];
  __shared__ float s_agg[16][65];

  const int t = threadIdx.x;
  const int node0 = blockIdx.x * 16;

  if (t < 17) s_pos[t] = pos[node0 + t];
  __syncthreads();

  const int tg = t >> 4, tl = t & 15;
  float a0 = 0.f, a1 = 0.f, a2 = 0.f, a3 = 0.f;
  for (int a = s_pos[tg]; a < s_pos[tg + 1]; ++a) {
    half4v v = *reinterpret_cast<const half4v*>(msg + (long)a * 64 + tl * 4);
    a0 += (float)v[0]; a1 += (float)v[1]; a2 += (float)v[2]; a3 += (float)v[3];
  }
  s_agg[tg][tl * 4 + 0] = a0;
  s_agg[tg][tl * 4 + 1] = a1;
  s_agg[tg][tl * 4 + 2] = a2;
  s_agg[tg][tl * 4 + 3] = a3;
  __syncthreads();

  // fused linear_down: out[node0+r] = (s_agg[r]/16) @ W_dn
  {
    const int r = t >> 4, c0 = (t & 15) * 4;
    float b0 = 0.f, b1 = 0.f, b2 = 0.f, b3 = 0.f;
    for (int k = 0; k < 64; ++k) {
      const float x = s_agg[r][k];
      const float4 wv = *reinterpret_cast<const float4*>(W_dn + k * 64 + c0);
      b0 = fmaf(x, wv.x, b0);
      b1 = fmaf(x, wv.y, b1);
      b2 = fmaf(x, wv.z, b2);
      b3 = fmaf(x, wv.w, b3);
    }
    float4 o = { b0 * 0.0625f, b1 * 0.0625f, b2 * 0.0625f, b3 * 0.0625f };
    *reinterpret_cast<float4*>(out + (long)(node0 + r) * 64 + c0) = o;
  }
}

extern "C" void kernel_launch(void* const* d_in, const int* in_sizes, int n_in,
                              void* d_out, int out_size, void* d_ws, size_t ws_size,
                              hipStream_t stream) {
  const float* nf   = (const float*)d_in[0];
  const float* ef   = (const float*)d_in[1];
  const float* rad  = (const float*)d_in[2];
  const int*   snd  = (const int*)d_in[3];
  const int*   rcv  = (const int*)d_in[4];
  const int*   msk  = (const int*)d_in[5];
  const float* W_up = (const float*)d_in[6];
  const float* W1   = (const float*)d_in[7];
  const float* W2   = (const float*)d_in[8];
  const float* W3   = (const float*)d_in[9];
  const float* W_dn = (const float*)d_in[10];
  float* out = (float*)d_out;

  // workspace layout (~109.5 MB)
  _Float16* msg  = (_Float16*)d_ws;                 // 800000*64 f16 = 102.4 MB
  _Float16* xbuf = msg + (size_t)NE * 64;           // 6.4 MB
  _Float16* w3p  = xbuf + (size_t)NN * 64;          // 32 KB
  _Float16* w2p  = w3p + 2048 * 8;                  // 8 KB
  int*      deg  = (int*)(w2p + 512 * 8);           // 200 KB
  int*      pos  = deg + NN;                        // 200 KB (+1)
  int*      cur  = pos + NN + 1;                    // 200 KB
  int*      bsum = cur + NN;                        // 1 KB
  int*      boff = bsum + 256;                      // 1 KB

  hipMemsetAsync(deg, 0, (size_t)NN * sizeof(int), stream);

  // linear_up + hist + pack in one grid-sliced launch
  prep_kernel<<<15635, 256, 0, stream>>>(nf, W_up, xbuf, rcv, deg, W3, W2, w3p, w2p);

  scan1_kernel<<<196, 256, 0, stream>>>(deg, bsum);
  scan2_kernel<<<1, 256, 0, stream>>>(bsum, boff);
  scan3_kernel<<<196, 256, 0, stream>>>(deg, boff, pos, cur);

  fused_tp_kernel<<<NE / 128, 256, 0, stream>>>(rad, ef, xbuf, snd, rcv, msk,
                                                W1, w2p, w3p, cur, msg);

  gather_down_kernel<<<NN / 16, 256, 0, stream>>>(msg, pos, W_dn, out);
}